// Round 15
// baseline (140.567 us; speedup 1.0000x reference)
//
#include <hip/hip_runtime.h>
#include <hip/hip_bf16.h>

#define NTOK 8192
#define CDIM 1024
#define FDIM 1024
#define NEXP 8
#define BM 256
#define BN 256
#define BK 64
#define NKT (CDIM / BK)   // 16 K-tiles
#define NWG 384           // 256 full-tile slots + 128 filler slots

typedef __attribute__((ext_vector_type(8))) short short8;
typedef __attribute__((ext_vector_type(4))) float f32x4;

union Pack4 { __hip_bfloat16 h[4]; unsigned long long v; };
union U4 { unsigned long long u; unsigned short s[4]; };

typedef const unsigned int __attribute__((address_space(1)))* gas_ptr;
typedef unsigned int __attribute__((address_space(3)))* las_ptr;

__device__ __forceinline__ void gload16(const void* g, void* l) {
    __builtin_amdgcn_global_load_lds(
        (gas_ptr)(unsigned long long)g,
        (las_ptr)(unsigned int)(unsigned long long)l,
        16, 0, 0);
}

__device__ __forceinline__ float bf2f(unsigned short v) {
    unsigned int t = (unsigned int)v << 16;
    return __uint_as_float(t);
}

// ---- inline worklist: derive (e, m0, off) from cnt (scalar, block-uniform) ----
__device__ __forceinline__ bool find_full_tile(const int* __restrict__ cnt, int tIdx,
                                               int& e, int& m0, int& off) {
    int acc = 0, s = 0;
    for (int ee = 0; ee < NEXP; ee++) {
        int me = cnt[ee * 16];
        int nf = me >> 8;
        if (tIdx < acc + nf) { e = ee; m0 = (tIdx - acc) << 8; off = s; return true; }
        acc += nf; s += me;
    }
    return false;
}
__device__ __forceinline__ bool find_fill_tile(const int* __restrict__ cnt, int tIdx,
                                               int& e, int& m0, int& off, int& me_out) {
    int acc = 0, s = 0;
    for (int ee = 0; ee < NEXP; ee++) {
        int me = cnt[ee * 16];
        int base = (me >> 8) << 8;
        int nr = (me - base + 127) >> 7;
        if (tIdx < acc + nr) {
            e = ee; m0 = base + ((tIdx - acc) << 7); off = s; me_out = me; return true;
        }
        acc += nr; s += me;
    }
    return false;
}

struct RouterSh {
    int lcnt[NEXP];
    int lt[NEXP][32];
    float lw[NEXP][32];
    int base[NEXP];
};

// ----- merged: blocks 0-511 = router (+x->bf16), blocks 512+ = weight transposes -----
// Router restructured: all 16 x-loads per lane issued upfront (one HBM-latency
// burst per wave instead of 4); rw chunks loaded once per (c,e), reused x4 tokens.
__global__ __launch_bounds__(256) void router_transpose(
    const float* __restrict__ x, const float* __restrict__ rw,
    __hip_bfloat16* __restrict__ xb,
    int* __restrict__ cnt, int* __restrict__ rows, float* __restrict__ wts,
    int* __restrict__ slotEI,
    const float* __restrict__ w1, const float* __restrict__ w2,
    __hip_bfloat16* __restrict__ w1t, __hip_bfloat16* __restrict__ w2t)
{
    __shared__ alignas(16) char shraw[64 * 65 * 4];
    const int bid = blockIdx.x;
    const int tid = threadIdx.x;

    if (bid < 512) {
        RouterSh* sh = reinterpret_cast<RouterSh*>(shraw);
        const int wv = tid >> 6, lane = tid & 63;
        if (tid < NEXP) sh->lcnt[tid] = 0;
        __syncthreads();

        const int n0t = bid * 16 + wv * 4;

        // 1) issue all 16 x loads (4 tokens x 4 chunks), static-indexed regs
        float4 xv[4][4];
#pragma unroll
        for (int tt = 0; tt < 4; tt++)
#pragma unroll
            for (int c = 0; c < 4; c++)
                xv[tt][c] = *(const float4*)(x + (size_t)(n0t + tt) * CDIM + c * 256 + lane * 4);

        // 2) convert + store xb
#pragma unroll
        for (int tt = 0; tt < 4; tt++)
#pragma unroll
            for (int c = 0; c < 4; c++) {
                Pack4 p4;
                p4.h[0] = __float2bfloat16(xv[tt][c].x);
                p4.h[1] = __float2bfloat16(xv[tt][c].y);
                p4.h[2] = __float2bfloat16(xv[tt][c].z);
                p4.h[3] = __float2bfloat16(xv[tt][c].w);
                *(unsigned long long*)(xb + (size_t)(n0t + tt) * CDIM + c * 256 + lane * 4) = p4.v;
            }

        // 3) dots from regs; rw loaded once per (c,e), reused for 4 tokens.
        //    Same per-token accumulation order as before (c ascending) -> bit-exact.
        float acc[4][NEXP];
#pragma unroll
        for (int tt = 0; tt < 4; tt++)
#pragma unroll
            for (int e = 0; e < NEXP; e++) acc[tt][e] = 0.f;
#pragma unroll
        for (int c = 0; c < 4; c++)
#pragma unroll
            for (int e = 0; e < NEXP; e++) {
                float4 w4 = *(const float4*)&rw[e * CDIM + c * 256 + lane * 4];
#pragma unroll
                for (int tt = 0; tt < 4; tt++)
                    acc[tt][e] += xv[tt][c].x * w4.x + xv[tt][c].y * w4.y +
                                  xv[tt][c].z * w4.z + xv[tt][c].w * w4.w;
            }

        // 4) reduce + top-2 per token (identical math/order to r14)
#pragma unroll
        for (int tt = 0; tt < 4; tt++)
#pragma unroll
            for (int e = 0; e < NEXP; e++)
#pragma unroll
                for (int s = 32; s > 0; s >>= 1)
                    acc[tt][e] += __shfl_xor(acc[tt][e], s);

        if (lane == 0) {
#pragma unroll
            for (int tt = 0; tt < 4; tt++) {
                const int n = n0t + tt;
                float mx = acc[tt][0];
#pragma unroll
                for (int e = 1; e < NEXP; e++) mx = fmaxf(mx, acc[tt][e]);
                float p[NEXP], se = 0.f;
#pragma unroll
                for (int e = 0; e < NEXP; e++) { p[e] = __expf(acc[tt][e] - mx); se += p[e]; }
                float inv = 1.f / se;
                int i0 = 0;
#pragma unroll
                for (int e = 1; e < NEXP; e++) if (p[e] > p[i0]) i0 = e;
                int i1 = (i0 == 0) ? 1 : 0;
#pragma unroll
                for (int e = 0; e < NEXP; e++) if (e != i0 && p[e] > p[i1]) i1 = e;
                int p0 = atomicAdd(&sh->lcnt[i0], 1);
                sh->lt[i0][p0] = n;
                sh->lw[i0][p0] = p[i0] * inv;
                int p1 = atomicAdd(&sh->lcnt[i1], 1);
                sh->lt[i1][p1] = n | (1 << 16);
                sh->lw[i1][p1] = p[i1] * inv;
            }
        }
        __syncthreads();
        if (tid < NEXP) sh->base[tid] = atomicAdd(&cnt[tid * 16], sh->lcnt[tid]);
        __syncthreads();
#pragma unroll
        for (int e = 0; e < NEXP; e++) {
            for (int i = tid; i < sh->lcnt[e]; i += 256) {
                int v = sh->lt[e][i];
                rows[e * NTOK + sh->base[e] + i] = v;
                wts [e * NTOK + sh->base[e] + i] = sh->lw[e][i];
                slotEI[2 * (v & 0xFFFF) + (v >> 16)] = (e << 14) | (sh->base[e] + i);
            }
        }
    } else {
        float (*t)[65] = reinterpret_cast<float(*)[65]>(shraw);
        const int zb = bid - 512;            // 0..4095
        const int z = zb >> 8;               // 0..15
        const float* src = (z < 8) ? w1 : w2;
        __hip_bfloat16* dst = (z < 8) ? w1t : w2t;
        const int e = z & 7;
        const int r0 = ((zb >> 4) & 15) * 64, c0 = (zb & 15) * 64;
        const int rr = tid >> 4;
        const int cc = (tid & 15) * 4;
#pragma unroll
        for (int j = 0; j < 4; j++) {
            int row = j * 16 + rr;
            float4 v = *(const float4*)(src + ((size_t)e * 1024 + r0 + row) * 1024 + c0 + cc);
            t[row][cc] = v.x; t[row][cc + 1] = v.y; t[row][cc + 2] = v.z; t[row][cc + 3] = v.w;
        }
        __syncthreads();
#pragma unroll
        for (int j = 0; j < 4; j++) {
            int trow = j * 16 + rr;
            Pack4 o;
#pragma unroll
            for (int k = 0; k < 4; k++) o.h[k] = __float2bfloat16(t[cc + k][trow]);
            *(unsigned long long*)(dst + ((size_t)e * 1024 + c0 + trow) * 1024 + r0 + cc) = o.v;
        }
    }
}

// ---- standalone router + transpose for the small-ws fallback path ----
__global__ __launch_bounds__(256) void router_kernel(
    const float* __restrict__ x, const float* __restrict__ rw,
    __hip_bfloat16* __restrict__ xb,
    int* __restrict__ cnt, int* __restrict__ rows, float* __restrict__ wts,
    int* __restrict__ slotEI)
{
    __shared__ RouterSh sh;
    const int tid = threadIdx.x;
    const int wv = tid >> 6, lane = tid & 63;
    if (tid < NEXP) sh.lcnt[tid] = 0;
    __syncthreads();
    for (int tt = 0; tt < 4; tt++) {
        const int n = blockIdx.x * 16 + wv * 4 + tt;
        float acc[NEXP];
#pragma unroll
        for (int e = 0; e < NEXP; e++) acc[e] = 0.f;
#pragma unroll
        for (int c0 = 0; c0 < CDIM; c0 += 256) {
            const size_t o = (size_t)n * CDIM + c0 + lane * 4;
            float4 xv = *(const float4*)(x + o);
            Pack4 p4;
            p4.h[0] = __float2bfloat16(xv.x); p4.h[1] = __float2bfloat16(xv.y);
            p4.h[2] = __float2bfloat16(xv.z); p4.h[3] = __float2bfloat16(xv.w);
            *(unsigned long long*)(xb + o) = p4.v;
#pragma unroll
            for (int e = 0; e < NEXP; e++) {
                float4 w4 = *(const float4*)&rw[e * CDIM + c0 + lane * 4];
                acc[e] += xv.x * w4.x + xv.y * w4.y + xv.z * w4.z + xv.w * w4.w;
            }
        }
#pragma unroll
        for (int e = 0; e < NEXP; e++) {
#pragma unroll
            for (int s = 32; s > 0; s >>= 1) acc[e] += __shfl_xor(acc[e], s);
        }
        if (lane == 0) {
            float mx = acc[0];
#pragma unroll
            for (int e = 1; e < NEXP; e++) mx = fmaxf(mx, acc[e]);
            float p[NEXP], se = 0.f;
#pragma unroll
            for (int e = 0; e < NEXP; e++) { p[e] = __expf(acc[e] - mx); se += p[e]; }
            float inv = 1.f / se;
            int i0 = 0;
#pragma unroll
            for (int e = 1; e < NEXP; e++) if (p[e] > p[i0]) i0 = e;
            int i1 = (i0 == 0) ? 1 : 0;
#pragma unroll
            for (int e = 0; e < NEXP; e++) if (e != i0 && p[e] > p[i1]) i1 = e;
            int p0 = atomicAdd(&sh.lcnt[i0], 1);
            sh.lt[i0][p0] = n; sh.lw[i0][p0] = p[i0] * inv;
            int p1 = atomicAdd(&sh.lcnt[i1], 1);
            sh.lt[i1][p1] = n | (1 << 16); sh.lw[i1][p1] = p[i1] * inv;
        }
    }
    __syncthreads();
    if (tid < NEXP) sh.base[tid] = atomicAdd(&cnt[tid * 16], sh.lcnt[tid]);
    __syncthreads();
#pragma unroll
    for (int e = 0; e < NEXP; e++) {
        for (int i = tid; i < sh.lcnt[e]; i += 256) {
            int v = sh.lt[e][i];
            rows[e * NTOK + sh.base[e] + i] = v;
            wts [e * NTOK + sh.base[e] + i] = sh.lw[e][i];
            slotEI[2 * (v & 0xFFFF) + (v >> 16)] = (e << 14) | (sh.base[e] + i);
        }
    }
}

__global__ __launch_bounds__(256) void transpose_conv(
    const float* __restrict__ src, __hip_bfloat16* __restrict__ dst)
{
    __shared__ float t[64][65];
    const int e = blockIdx.z;
    const int r0 = blockIdx.x * 64, c0 = blockIdx.y * 64;
    const int tid = threadIdx.x;
    const int rr = tid >> 4;
    const int cc = (tid & 15) * 4;
#pragma unroll
    for (int j = 0; j < 4; j++) {
        int row = j * 16 + rr;
        float4 v = *(const float4*)(src + ((size_t)e * 1024 + r0 + row) * 1024 + c0 + cc);
        t[row][cc] = v.x; t[row][cc + 1] = v.y; t[row][cc + 2] = v.z; t[row][cc + 3] = v.w;
    }
    __syncthreads();
#pragma unroll
    for (int j = 0; j < 4; j++) {
        int trow = j * 16 + rr;
        Pack4 o;
#pragma unroll
        for (int k = 0; k < 4; k++) o.h[k] = __float2bfloat16(t[cc + k][trow]);
        *(unsigned long long*)(dst + ((size_t)e * 1024 + c0 + trow) * 1024 + r0 + cc) = o.v;
    }
}

// ======== 8-phase 256x256 GEMM core, deep-staged (proven r12/r14 schedule) ========
#define STAGE_A(buf, h, kt) { \
    gload16(asrc[2*(h)]   + (kt)*BK, &smem[buf][0][((2*(h))*512   + wv*64)*8]); \
    gload16(asrc[2*(h)+1] + (kt)*BK, &smem[buf][0][((2*(h)+1)*512 + wv*64)*8]); }
#define STAGE_B(buf, h, kt) { \
    gload16(bsrc[2*(h)]   + (kt)*BK, &smem[buf][1][((2*(h))*512   + wv*64)*8]); \
    gload16(bsrc[2*(h)+1] + (kt)*BK, &smem[buf][1][((2*(h)+1)*512 + wv*64)*8]); }
#define PH_READ_A(buf, mh, ks) { \
    const int cs_ = (((ks)*4 + fq) ^ fx) * 8; \
    _Pragma("unroll") \
    for (int i_ = 0; i_ < 4; i_++) \
        af[i_] = *(const short8*)&smem[buf][0][(wr*128 + (mh)*64 + i_*16 + fr)*64 + cs_]; }
#define PH_READ_B(buf, ks) { \
    const int cs_ = (((ks)*4 + fq) ^ fx) * 8; \
    _Pragma("unroll") \
    for (int n_ = 0; n_ < 4; n_++) \
        bfv[n_] = *(const short8*)&smem[buf][1][(wc*64 + n_*16 + fr)*64 + cs_]; }
#define PH_MFMA(mh) { \
    __builtin_amdgcn_s_setprio(1); \
    _Pragma("unroll") \
    for (int i_ = 0; i_ < 4; i_++) \
        _Pragma("unroll") \
        for (int n_ = 0; n_ < 4; n_++) \
            acc[(mh)*4 + i_][n_] = __builtin_amdgcn_mfma_f32_16x16x32_bf16( \
                af[i_], bfv[n_], acc[(mh)*4 + i_][n_], 0, 0, 0); \
    __builtin_amdgcn_s_setprio(0); }
#define SBAR { \
    __builtin_amdgcn_sched_barrier(0); \
    __builtin_amdgcn_s_barrier(); \
    __builtin_amdgcn_sched_barrier(0); }

// Stage placement (region-safe, deep):
//  buf1-A @ p1, buf0-B @ p4, buf0-A @ p5, buf1-B @ p8; vmcnt(4) at p4/p8.
#define KLOOP_8PHASE \
    STAGE_A(0, 0, 0); STAGE_A(0, 1, 0); STAGE_B(0, 0, 0); STAGE_B(0, 1, 0); \
    STAGE_B(1, 0, 1); STAGE_B(1, 1, 1); \
    asm volatile("s_waitcnt vmcnt(4)" ::: "memory"); \
    SBAR; \
    _Pragma("unroll 1") \
    for (int j = 0; j < NKT / 2; j++) { \
        const int t2 = 2 * j; \
        const bool full = (j < NKT / 2 - 1); \
        short8 af[4], bfv[4]; \
        /* p1 */ \
        PH_READ_A(0, 0, 0); PH_READ_B(0, 0); \
        STAGE_A(1, 0, t2 + 1); STAGE_A(1, 1, t2 + 1); \
        SBAR; PH_MFMA(0); \
        /* p2 */ \
        PH_READ_A(0, 1, 0); \
        SBAR; PH_MFMA(1); \
        /* p3 */ \
        PH_READ_A(0, 0, 1); PH_READ_B(0, 1); \
        SBAR; PH_MFMA(0); \
        /* p4 */ \
        PH_READ_A(0, 1, 1); \
        if (full) { \
            STAGE_B(0, 0, t2 + 2); STAGE_B(0, 1, t2 + 2); \
            asm volatile("s_waitcnt vmcnt(4)" ::: "memory"); \
        } else { \
            asm volatile("s_waitcnt vmcnt(0)" ::: "memory"); \
        } \
        SBAR; PH_MFMA(1); \
        /* p5 */ \
        PH_READ_A(1, 0, 0); PH_READ_B(1, 0); \
        if (full) { STAGE_A(0, 0, t2 + 2); STAGE_A(0, 1, t2 + 2); } \
        SBAR; PH_MFMA(0); \
        /* p6 */ \
        PH_READ_A(1, 1, 0); \
        SBAR; PH_MFMA(1); \
        /* p7 */ \
        PH_READ_A(1, 0, 1); PH_READ_B(1, 1); \
        SBAR; PH_MFMA(0); \
        /* p8 */ \
        PH_READ_A(1, 1, 1); \
        if (full) { \
            STAGE_B(1, 0, t2 + 3); STAGE_B(1, 1, t2 + 3); \
            asm volatile("s_waitcnt vmcnt(4)" ::: "memory"); \
        } \
        SBAR; PH_MFMA(1); \
    }

// ---------------- GEMM1: hid = relu(Xb[rows] @ w1t^T) ----------------
__global__ __launch_bounds__(512, 1) void moe_gemm1(
    const __hip_bfloat16* __restrict__ xb, const __hip_bfloat16* __restrict__ w1t,
    const int* __restrict__ cnt, const int* __restrict__ rows,
    __hip_bfloat16* __restrict__ hid)
{
    const int bid = blockIdx.x;
    const int tid = threadIdx.x;
    const int lane = tid & 63, wv = tid >> 6;
    const int fr = lane & 15, fq = lane >> 4;
    const int fx = fr & 7;

    __shared__ alignas(16) __hip_bfloat16 smem[2][2][BM * BK];   // 128 KB

    const int swz8 = (((tid & 7) ^ ((tid >> 3) & 7))) * 8;

    if (bid < 256) {
        const int wid = (bid & 7) * 32 + (bid >> 3);
        const int t = wid >> 2;
        int e, m0, off;
        if (!find_full_tile(cnt, t, e, m0, off)) return;
        const int n0 = (wid & 3) * BN;
        const int wr = wv >> 2, wc = wv & 3;

        const __hip_bfloat16* asrc[4];
        const __hip_bfloat16* bsrc[4];
#pragma unroll
        for (int i = 0; i < 4; i++) {
            int row = i * 64 + (tid >> 3);
            int tok = rows[e * NTOK + m0 + row] & 0xFFFF;
            asrc[i] = xb + (size_t)tok * CDIM + swz8;
            bsrc[i] = w1t + ((size_t)e * FDIM + n0 + row) * CDIM + swz8;
        }

        f32x4 acc[8][4] = {};
        KLOOP_8PHASE;
        __syncthreads();

        __hip_bfloat16 (*Cl)[BN] = reinterpret_cast<__hip_bfloat16(*)[BN]>(&smem[0][0][0]);
#pragma unroll
        for (int m = 0; m < 8; m++)
#pragma unroll
            for (int n = 0; n < 4; n++)
#pragma unroll
                for (int r = 0; r < 4; r++) {
                    int il = wr * 128 + m * 16 + fq * 4 + r;
                    float v = acc[m][n][r];
                    Cl[il][wc * 64 + n * 16 + fr] = __float2bfloat16(v > 0.f ? v : 0.f);
                }
        __syncthreads();
#pragma unroll
        for (int i = 0; i < 16; i++) {
            int chunk = i * 512 + tid;
            int row = chunk >> 5, c8 = (chunk & 31) * 8;
            *(short8*)(hid + (size_t)(off + m0 + row) * FDIM + n0 + c8) =
                *(const short8*)&Cl[row][c8];
        }
    } else {
        // ---- 128x128 filler path ----
        const int f = bid - 256;
        const int t = f >> 3;
        int e, m0, off, me;
        if (!find_fill_tile(cnt, t, e, m0, off, me)) return;
        const int n0 = (f & 7) * 128;
        const int wr2 = wv >> 2, wc2 = wv & 3;

        const __hip_bfloat16* asrcF[2];
        const __hip_bfloat16* bsrcF[2];
#pragma unroll
        for (int i = 0; i < 2; i++) {
            int row = i * 64 + (tid >> 3);
            int gi = m0 + row;
            int ri = gi < me ? gi : me - 1;
            int tok = rows[e * NTOK + ri] & 0xFFFF;
            asrcF[i] = xb + (size_t)tok * CDIM + swz8;
            bsrcF[i] = w1t + ((size_t)e * FDIM + n0 + row) * CDIM + swz8;
        }

        f32x4 accF[4][2] = {};

#pragma unroll
        for (int i = 0; i < 2; i++) {
            gload16(asrcF[i], &smem[0][0][(i * 512 + wv * 64) * 8]);
            gload16(bsrcF[i], &smem[0][1][(i * 512 + wv * 64) * 8]);
        }

        int cur = 0;
        for (int kt = 0; kt < NKT; kt++) {
            __builtin_amdgcn_s_barrier();
            if (kt + 1 < NKT) {
                const int k1 = (kt + 1) * BK;
#pragma unroll
                for (int i = 0; i < 2; i++) {
                    gload16(asrcF[i] + k1, &smem[cur ^ 1][0][(i * 512 + wv * 64) * 8]);
                    gload16(bsrcF[i] + k1, &smem[cur ^ 1][1][(i * 512 + wv * 64) * 8]);
                }
                asm volatile("s_waitcnt vmcnt(4)" ::: "memory");
            } else {
                asm volatile("s_waitcnt vmcnt(0)" ::: "memory");
            }
            __builtin_amdgcn_s_barrier();
            __builtin_amdgcn_sched_barrier(0);
#pragma unroll
            for (int ks = 0; ks < 2; ks++) {
                short8 afF[4], bfF[2];
                const int cs = ((ks * 4 + fq) ^ fx) * 8;
#pragma unroll
                for (int m = 0; m < 4; m++)
                    afF[m] = *(const short8*)&smem[cur][0][(wr2 * 64 + m * 16 + fr) * 64 + cs];
#pragma unroll
                for (int n = 0; n < 2; n++)
                    bfF[n] = *(const short8*)&smem[cur][1][(wc2 * 32 + n * 16 + fr) * 64 + cs];
#pragma unroll
                for (int m = 0; m < 4; m++)
#pragma unroll
                    for (int n = 0; n < 2; n++)
                        accF[m][n] = __builtin_amdgcn_mfma_f32_16x16x32_bf16(
                            afF[m], bfF[n], accF[m][n], 0, 0, 0);
            }
            cur ^= 1;
        }
        __syncthreads();

        __hip_bfloat16 (*Cl)[128] = reinterpret_cast<__hip_bfloat16(*)[128]>(&smem[0][0][0]);
#pragma unroll
        for (int m = 0; m < 4; m++)
#pragma unroll
            for (int n = 0; n < 2; n++)
#pragma unroll
                for (int r = 0; r < 4; r++) {
                    int il = wr2 * 64 + m * 16 + fq * 4 + r;
                    float v = accF[m][n][r];
                    Cl[il][wc2 * 32 + n * 16 + fr] = __float2bfloat16(v > 0.f ? v : 0.f);
                }
        __syncthreads();
#pragma unroll
        for (int i = 0; i < 4; i++) {
            int chunk = i * 512 + tid;
            int row = chunk >> 4, c8 = (chunk & 15) * 8;
            int gi = m0 + row;
            if (gi < me)
                *(short8*)(hid + (size_t)(off + gi) * FDIM + n0 + c8) =
                    *(const short8*)&Cl[row][c8];
        }
    }
}

// ------- GEMM2: ybuf[slot] = wt * (hid @ w2t^T) (or atomic fallback) -------
__global__ __launch_bounds__(512, 1) void moe_gemm2(
    const __hip_bfloat16* __restrict__ hid, const __hip_bfloat16* __restrict__ w2t,
    const int* __restrict__ cnt, const int* __restrict__ rows,
    const float* __restrict__ wts, __hip_bfloat16* __restrict__ ybuf,
    float* __restrict__ out)
{
    const int bid = blockIdx.x;
    const int tid = threadIdx.x;
    const int lane = tid & 63, wv = tid >> 6;
    const int fr = lane & 15, fq = lane >> 4;
    const int fx = fr & 7;

    __shared__ alignas(16) __hip_bfloat16 smem[2][2][BM * BK];
    __shared__ int rtok[BM];
    __shared__ float rwt[BM];

    const int swz8 = (((tid & 7) ^ ((tid >> 3) & 7))) * 8;

    if (bid < 256) {
        const int wid = (bid & 7) * 32 + (bid >> 3);
        const int t = wid >> 2;
        int e, m0, off;
        if (!find_full_tile(cnt, t, e, m0, off)) return;
        const int n0 = (wid & 3) * BN;
        const int wr = wv >> 2, wc = wv & 3;

        if (tid < BM) {
            rtok[tid] = rows[e * NTOK + m0 + tid] & 0xFFFF;
            rwt[tid] = wts[e * NTOK + m0 + tid];
        }
        __syncthreads();

        const __hip_bfloat16* asrc[4];
        const __hip_bfloat16* bsrc[4];
#pragma unroll
        for (int i = 0; i < 4; i++) {
            int row = i * 64 + (tid >> 3);
            asrc[i] = hid + (size_t)(off + m0 + row) * FDIM + swz8;
            bsrc[i] = w2t + ((size_t)e * CDIM + n0 + row) * FDIM + swz8;
        }

        f32x4 acc[8][4] = {};
        KLOOP_8PHASE;
        __syncthreads();

        if (ybuf) {
            __hip_bfloat16 (*Cl)[BN] = reinterpret_cast<__hip_bfloat16(*)[BN]>(&smem[0][0][0]);
#pragma unroll
            for (int m = 0; m < 8; m++)
#pragma unroll
                for (int n = 0; n < 4; n++)
#pragma unroll
                    for (int r = 0; r < 4; r++) {
                        int il = wr * 128 + m * 16 + fq * 4 + r;
                        Cl[il][wc * 64 + n * 16 + fr] =
                            __float2bfloat16(rwt[il] * acc[m][n][r]);
                    }
            __syncthreads();
#pragma unroll
            for (int i = 0; i < 16; i++) {
                int chunk = i * 512 + tid;
                int row = chunk >> 5, c8 = (chunk & 31) * 8;
                *(short8*)(ybuf + (size_t)(off + m0 + row) * CDIM + n0 + c8) =
                    *(const short8*)&Cl[row][c8];
            }
        } else {
#pragma unroll
            for (int m = 0; m < 8; m++)
#pragma unroll
                for (int n = 0; n < 4; n++)
#pragma unroll
                    for (int r = 0; r < 4; r++) {
                        int il = wr * 128 + m * 16 + fq * 4 + r;
                        atomicAdd(&out[(size_t)rtok[il] * CDIM + n0 + wc * 64 + n * 16 + fr],
                                  rwt[il] * acc[m][n][r]);
                    }
        }
    } else {
        // ---- 128x128 filler path ----
        const int f = bid - 256;
        const int t = f >> 3;
        int e, m0, off, me;
        if (!find_fill_tile(cnt, t, e, m0, off, me)) return;
        const int n0 = (f & 7) * 128;
        const int wr2 = wv >> 2, wc2 = wv & 3;

        if (tid < 128) {
            int gi = m0 + tid;
            int ri = gi < me ? gi : me - 1;
            rtok[tid] = rows[e * NTOK + ri] & 0xFFFF;
            rwt[tid] = gi < me ? wts[e * NTOK + ri] : 0.f;
        }
        __syncthreads();

        const __hip_bfloat16* asrcF[2];
        const __hip_bfloat16* bsrcF[2];
#pragma unroll
        for (int i = 0; i < 2; i++) {
            int row = i * 64 + (tid >> 3);
            int gi = m0 + row;
            int ri = gi < me ? gi : me - 1;
            asrcF[i] = hid + (size_t)(off + ri) * FDIM + swz8;
            bsrcF[i] = w2t + ((size_t)e * CDIM + n0 + row) * FDIM + swz8;
        }

        f32x4 accF[4][2] = {};

#pragma unroll
        for (int i = 0; i < 2; i++) {
            gload16(asrcF[i], &smem[0][0][(i * 512 + wv * 64) * 8]);
            gload16(bsrcF[i], &smem[0][1][(i * 512 + wv * 64) * 8]);
        }

        int cur = 0;
        for (int kt = 0; kt < NKT; kt++) {
            __builtin_amdgcn_s_barrier();
            if (kt + 1 < NKT) {
                const int k1 = (kt + 1) * BK;
#pragma unroll
                for (int i = 0; i < 2; i++) {
                    gload16(asrcF[i] + k1, &smem[cur ^ 1][0][(i * 512 + wv * 64) * 8]);
                    gload16(bsrcF[i] + k1, &smem[cur ^ 1][1][(i * 512 + wv * 64) * 8]);
                }
                asm volatile("s_waitcnt vmcnt(4)" ::: "memory");
            } else {
                asm volatile("s_waitcnt vmcnt(0)" ::: "memory");
            }
            __builtin_amdgcn_s_barrier();
            __builtin_amdgcn_sched_barrier(0);
#pragma unroll
            for (int ks = 0; ks < 2; ks++) {
                short8 afF[4], bfF[2];
                const int cs = ((ks * 4 + fq) ^ fx) * 8;
#pragma unroll
                for (int m = 0; m < 4; m++)
                    afF[m] = *(const short8*)&smem[cur][0][(wr2 * 64 + m * 16 + fr) * 64 + cs];
#pragma unroll
                for (int n = 0; n < 2; n++)
                    bfF[n] = *(const short8*)&smem[cur][1][(wc2 * 32 + n * 16 + fr) * 64 + cs];
#pragma unroll
                for (int m = 0; m < 4; m++)
#pragma unroll
                    for (int n = 0; n < 2; n++)
                        accF[m][n] = __builtin_amdgcn_mfma_f32_16x16x32_bf16(
                            afF[m], bfF[n], accF[m][n], 0, 0, 0);
            }
            cur ^= 1;
        }
        __syncthreads();

        if (ybuf) {
            __hip_bfloat16 (*Cl)[128] = reinterpret_cast<__hip_bfloat16(*)[128]>(&smem[0][0][0]);
#pragma unroll
            for (int m = 0; m < 4; m++)
#pragma unroll
                for (int n = 0; n < 2; n++)
#pragma unroll
                    for (int r = 0; r < 4; r++) {
                        int il = wr2 * 64 + m * 16 + fq * 4 + r;
                        Cl[il][wc2 * 32 + n * 16 + fr] =
                            __float2bfloat16(rwt[il] * accF[m][n][r]);
                    }
            __syncthreads();
#pragma unroll
            for (int i = 0; i < 4; i++) {
                int chunk = i * 512 + tid;
                int row = chunk >> 4, c8 = (chunk & 15) * 8;
                int gi = m0 + row;
                if (gi < me)
                    *(short8*)(ybuf + (size_t)(off + gi) * CDIM + n0 + c8) =
                        *(const short8*)&Cl[row][c8];
            }
        } else {
#pragma unroll
            for (int m = 0; m < 4; m++)
#pragma unroll
                for (int n = 0; n < 2; n++)
#pragma unroll
                    for (int r = 0; r < 4; r++) {
                        int il = wr2 * 64 + m * 16 + fq * 4 + r;
                        int gi = m0 + il;
                        if (gi < me)
                            atomicAdd(&out[(size_t)rtok[il] * CDIM + n0 + wc2 * 32 + n * 16 + fr],
                                      rwt[il] * accF[m][n][r]);
                    }
        }
    }
}

// ---------------- gather: out[n] = y[slot0] + y[slot1] ----------------
__global__ __launch_bounds__(256) void gather_out(
    const __hip_bfloat16* __restrict__ yb, const int* __restrict__ slotEI,
    const int* __restrict__ cnt, float* __restrict__ out)
{
    for (int n = blockIdx.x; n < NTOK; n += gridDim.x) {
        const int v0 = slotEI[2 * n], v1 = slotEI[2 * n + 1];
        int e0 = v0 >> 14, e1 = v1 >> 14;
        int s0 = v0 & 0x3FFF, s1 = v1 & 0x3FFF;
        for (int ee = 0; ee < NEXP; ee++) {
            int me = cnt[ee * 16];
            if (ee < e0) s0 += me;
            if (ee < e1) s1 += me;
        }
        const int c = threadIdx.x * 4;
        U4 a, b;
        a.u = *(const unsigned long long*)(yb + (size_t)s0 * CDIM + c);
        b.u = *(const unsigned long long*)(yb + (size_t)s1 * CDIM + c);
        float4 o;
        o.x = bf2f(a.s[0]) + bf2f(b.s[0]);
        o.y = bf2f(a.s[1]) + bf2f(b.s[1]);
        o.z = bf2f(a.s[2]) + bf2f(b.s[2]);
        o.w = bf2f(a.s[3]) + bf2f(b.s[3]);
        *(float4*)(out + (size_t)n * CDIM + c) = o;
    }
}

// ---------------- launch ----------------
extern "C" void kernel_launch(void* const* d_in, const int* in_sizes, int n_in,
                              void* d_out, int out_size, void* d_ws, size_t ws_size,
                              hipStream_t stream)
{
    const float* x  = (const float*)d_in[0];
    const float* rw = (const float*)d_in[1];
    const float* w1 = (const float*)d_in[2];
    const float* w2 = (const float*)d_in[3];
    float* out = (float*)d_out;
    char* ws = (char*)d_ws;

    int* cnt  = (int*)ws;                                  // 8 counters, 64B stride
    int* rows = (int*)(ws + 4096);                         // [E][NTOK]
    float* wts = (float*)(ws + 4096 + NEXP * NTOK * 4);
    int* slotEI = (int*)(ws + 4096 + 2 * NEXP * NTOK * 4); // [NTOK][2]

    hipMemsetAsync(cnt, 0, 1024, stream);

    const bool big = ws_size >= ((size_t)81 << 20);
    if (big) {
        // layout: xb 1-17, w1t 17-33, w2t 33-49, hid 49-81, ybuf overlays 1-33
        __hip_bfloat16* xb  = (__hip_bfloat16*)(ws + (1u << 20));
        __hip_bfloat16* w1t = (__hip_bfloat16*)(ws + (17u << 20));
        __hip_bfloat16* w2t = (__hip_bfloat16*)(ws + (33u << 20));
        __hip_bfloat16* hid = (__hip_bfloat16*)(ws + (49u << 20));
        __hip_bfloat16* ybuf = (__hip_bfloat16*)(ws + (1u << 20));  // xb+w1t dead after gemm1

        router_transpose<<<512 + 4096, 256, 0, stream>>>(
            x, rw, xb, cnt, rows, wts, slotEI, w1, w2, w1t, w2t);
        moe_gemm1<<<NWG, 512, 0, stream>>>(xb, w1t, cnt, rows, hid);
        moe_gemm2<<<NWG, 512, 0, stream>>>(hid, w2t, cnt, rows, wts, ybuf, out);
        gather_out<<<2048, 256, 0, stream>>>(ybuf, slotEI, cnt, out);
    } else {
        // compact fallback: w2t aliases w1t (transposed after gemm1), atomic epilogue
        __hip_bfloat16* xb  = (__hip_bfloat16*)(ws + (1u << 20));
        __hip_bfloat16* w1t = (__hip_bfloat16*)(ws + (17u << 20));
        __hip_bfloat16* hid = (__hip_bfloat16*)(ws + (33u << 20));
        __hip_bfloat16* w2t = w1t;

        hipMemsetAsync(d_out, 0, (size_t)out_size * sizeof(float), stream);
        router_kernel<<<NTOK / 16, 256, 0, stream>>>(x, rw, xb, cnt, rows, wts, slotEI);
        transpose_conv<<<dim3(16, 16, NEXP), 256, 0, stream>>>(w1, w1t);
        moe_gemm1<<<NWG, 512, 0, stream>>>(xb, w1t, cnt, rows, hid);
        transpose_conv<<<dim3(16, 16, NEXP), 256, 0, stream>>>(w2, w2t);
        moe_gemm2<<<NWG, 512, 0, stream>>>(hid, w2t, cnt, rows, wts, nullptr, out);
    }
}

// Round 16
// 136.627 us; speedup vs baseline: 1.0288x; 1.0288x over previous
//
#include <hip/hip_runtime.h>
#include <hip/hip_bf16.h>

#define NTOK 8192
#define CDIM 1024
#define FDIM 1024
#define NEXP 8
#define BM 256
#define BN 256
#define BK 64
#define NKT (CDIM / BK)   // 16 K-tiles
#define NWG 384           // 256 full-tile slots + 128 filler slots

typedef __attribute__((ext_vector_type(8))) short short8;
typedef __attribute__((ext_vector_type(4))) float f32x4;

union Pack4 { __hip_bfloat16 h[4]; unsigned long long v; };
union U4 { unsigned long long u; unsigned short s[4]; };

typedef const unsigned int __attribute__((address_space(1)))* gas_ptr;
typedef unsigned int __attribute__((address_space(3)))* las_ptr;

__device__ __forceinline__ void gload16(const void* g, void* l) {
    __builtin_amdgcn_global_load_lds(
        (gas_ptr)(unsigned long long)g,
        (las_ptr)(unsigned int)(unsigned long long)l,
        16, 0, 0);
}

__device__ __forceinline__ float bf2f(unsigned short v) {
    unsigned int t = (unsigned int)v << 16;
    return __uint_as_float(t);
}

// ---- inline worklist: derive (e, m0, off) from cnt (scalar, block-uniform) ----
__device__ __forceinline__ bool find_full_tile(const int* __restrict__ cnt, int tIdx,
                                               int& e, int& m0, int& off) {
    int acc = 0, s = 0;
    for (int ee = 0; ee < NEXP; ee++) {
        int me = cnt[ee * 16];
        int nf = me >> 8;
        if (tIdx < acc + nf) { e = ee; m0 = (tIdx - acc) << 8; off = s; return true; }
        acc += nf; s += me;
    }
    return false;
}
__device__ __forceinline__ bool find_fill_tile(const int* __restrict__ cnt, int tIdx,
                                               int& e, int& m0, int& off, int& me_out) {
    int acc = 0, s = 0;
    for (int ee = 0; ee < NEXP; ee++) {
        int me = cnt[ee * 16];
        int base = (me >> 8) << 8;
        int nr = (me - base + 127) >> 7;
        if (tIdx < acc + nr) {
            e = ee; m0 = base + ((tIdx - acc) << 7); off = s; me_out = me; return true;
        }
        acc += nr; s += me;
    }
    return false;
}

// router shared state: staged x (2x16KB dbuf) + histogram
struct RouterSh2 {
    float xs[2][16][256];   // 32 KB
    int lcnt[NEXP];
    int lt[NEXP][32];
    float lw[NEXP][32];
    int base[NEXP];
};

// ----- merged: blocks 0-511 = router (+x->bf16), blocks 512+ = weight transposes -----
// Router x-path: global_load_lds double-buffer with counted vmcnt (r8-proven loop).
__global__ __launch_bounds__(256) void router_transpose(
    const float* __restrict__ x, const float* __restrict__ rw,
    __hip_bfloat16* __restrict__ xb,
    int* __restrict__ cnt, int* __restrict__ rows, float* __restrict__ wts,
    int* __restrict__ slotEI,
    const float* __restrict__ w1, const float* __restrict__ w2,
    __hip_bfloat16* __restrict__ w1t, __hip_bfloat16* __restrict__ w2t)
{
    __shared__ alignas(16) char shraw[sizeof(RouterSh2)];
    const int bid = blockIdx.x;
    const int tid = threadIdx.x;

    if (bid < 512) {
        RouterSh2* sh = reinterpret_cast<RouterSh2*>(shraw);
        const int wv = tid >> 6, lane = tid & 63;
        if (tid < NEXP) sh->lcnt[tid] = 0;
        const int n0b = bid * 16;

        // prologue: stage chunk 0 into buf 0 (4 gload16/thread)
#pragma unroll
        for (int i = 0; i < 4; i++)
            gload16(x + (size_t)(n0b + i * 4 + wv) * CDIM + lane * 4,
                    (char*)&sh->xs[0][0][0] + i * 4096 + wv * 1024);

        float acc[4][NEXP];
#pragma unroll
        for (int tt = 0; tt < 4; tt++)
#pragma unroll
            for (int e = 0; e < NEXP; e++) acc[tt][e] = 0.f;

        int cur = 0;
        for (int c = 0; c < 4; c++) {
            __builtin_amdgcn_s_barrier();     // prior-iter reads of buf[cur^1] done
            if (c + 1 < 4) {
#pragma unroll
                for (int i = 0; i < 4; i++)
                    gload16(x + (size_t)(n0b + i * 4 + wv) * CDIM + (c + 1) * 256 + lane * 4,
                            (char*)&sh->xs[cur ^ 1][0][0] + i * 4096 + wv * 1024);
                asm volatile("s_waitcnt vmcnt(4)" ::: "memory");   // chunk c staged
            } else {
                asm volatile("s_waitcnt vmcnt(0)" ::: "memory");
            }
            __builtin_amdgcn_s_barrier();     // all waves' chunk-c loads complete
            __builtin_amdgcn_sched_barrier(0);

            // rw chunk hoisted once, reused across this wave's 4 tokens
            float4 w4[NEXP];
#pragma unroll
            for (int e = 0; e < NEXP; e++)
                w4[e] = *(const float4*)&rw[e * CDIM + c * 256 + lane * 4];

#pragma unroll
            for (int tt = 0; tt < 4; tt++) {
                float4 xv = *(const float4*)&sh->xs[cur][wv * 4 + tt][lane * 4];
                Pack4 p4;
                p4.h[0] = __float2bfloat16(xv.x); p4.h[1] = __float2bfloat16(xv.y);
                p4.h[2] = __float2bfloat16(xv.z); p4.h[3] = __float2bfloat16(xv.w);
                *(unsigned long long*)(xb + (size_t)(n0b + wv * 4 + tt) * CDIM
                                       + c * 256 + lane * 4) = p4.v;
#pragma unroll
                for (int e = 0; e < NEXP; e++)
                    acc[tt][e] += xv.x * w4[e].x + xv.y * w4[e].y +
                                  xv.z * w4[e].z + xv.w * w4[e].w;
            }
            cur ^= 1;
        }

        // reduce + top-2 per token (identical math/order to r14/r15)
#pragma unroll
        for (int tt = 0; tt < 4; tt++)
#pragma unroll
            for (int e = 0; e < NEXP; e++)
#pragma unroll
                for (int s = 32; s > 0; s >>= 1)
                    acc[tt][e] += __shfl_xor(acc[tt][e], s);

        if (lane == 0) {
#pragma unroll
            for (int tt = 0; tt < 4; tt++) {
                const int n = n0b + wv * 4 + tt;
                float mx = acc[tt][0];
#pragma unroll
                for (int e = 1; e < NEXP; e++) mx = fmaxf(mx, acc[tt][e]);
                float p[NEXP], se = 0.f;
#pragma unroll
                for (int e = 0; e < NEXP; e++) { p[e] = __expf(acc[tt][e] - mx); se += p[e]; }
                float inv = 1.f / se;
                int i0 = 0;
#pragma unroll
                for (int e = 1; e < NEXP; e++) if (p[e] > p[i0]) i0 = e;
                int i1 = (i0 == 0) ? 1 : 0;
#pragma unroll
                for (int e = 0; e < NEXP; e++) if (e != i0 && p[e] > p[i1]) i1 = e;
                int p0 = atomicAdd(&sh->lcnt[i0], 1);
                sh->lt[i0][p0] = n;
                sh->lw[i0][p0] = p[i0] * inv;
                int p1 = atomicAdd(&sh->lcnt[i1], 1);
                sh->lt[i1][p1] = n | (1 << 16);
                sh->lw[i1][p1] = p[i1] * inv;
            }
        }
        __syncthreads();
        if (tid < NEXP) sh->base[tid] = atomicAdd(&cnt[tid * 16], sh->lcnt[tid]);
        __syncthreads();
#pragma unroll
        for (int e = 0; e < NEXP; e++) {
            for (int i = tid; i < sh->lcnt[e]; i += 256) {
                int v = sh->lt[e][i];
                rows[e * NTOK + sh->base[e] + i] = v;
                wts [e * NTOK + sh->base[e] + i] = sh->lw[e][i];
                slotEI[2 * (v & 0xFFFF) + (v >> 16)] = (e << 14) | (sh->base[e] + i);
            }
        }
    } else {
        float (*t)[65] = reinterpret_cast<float(*)[65]>(shraw);
        const int zb = bid - 512;            // 0..4095
        const int z = zb >> 8;               // 0..15
        const float* src = (z < 8) ? w1 : w2;
        __hip_bfloat16* dst = (z < 8) ? w1t : w2t;
        const int e = z & 7;
        const int r0 = ((zb >> 4) & 15) * 64, c0 = (zb & 15) * 64;
        const int rr = tid >> 4;
        const int cc = (tid & 15) * 4;
#pragma unroll
        for (int j = 0; j < 4; j++) {
            int row = j * 16 + rr;
            float4 v = *(const float4*)(src + ((size_t)e * 1024 + r0 + row) * 1024 + c0 + cc);
            t[row][cc] = v.x; t[row][cc + 1] = v.y; t[row][cc + 2] = v.z; t[row][cc + 3] = v.w;
        }
        __syncthreads();
#pragma unroll
        for (int j = 0; j < 4; j++) {
            int trow = j * 16 + rr;
            Pack4 o;
#pragma unroll
            for (int k = 0; k < 4; k++) o.h[k] = __float2bfloat16(t[cc + k][trow]);
            *(unsigned long long*)(dst + ((size_t)e * 1024 + c0 + trow) * 1024 + r0 + cc) = o.v;
        }
    }
}

// ---- standalone router + transpose for the small-ws fallback path ----
struct RouterSh {
    int lcnt[NEXP];
    int lt[NEXP][32];
    float lw[NEXP][32];
    int base[NEXP];
};

__global__ __launch_bounds__(256) void router_kernel(
    const float* __restrict__ x, const float* __restrict__ rw,
    __hip_bfloat16* __restrict__ xb,
    int* __restrict__ cnt, int* __restrict__ rows, float* __restrict__ wts,
    int* __restrict__ slotEI)
{
    __shared__ RouterSh sh;
    const int tid = threadIdx.x;
    const int wv = tid >> 6, lane = tid & 63;
    if (tid < NEXP) sh.lcnt[tid] = 0;
    __syncthreads();
    for (int tt = 0; tt < 4; tt++) {
        const int n = blockIdx.x * 16 + wv * 4 + tt;
        float acc[NEXP];
#pragma unroll
        for (int e = 0; e < NEXP; e++) acc[e] = 0.f;
#pragma unroll
        for (int c0 = 0; c0 < CDIM; c0 += 256) {
            const size_t o = (size_t)n * CDIM + c0 + lane * 4;
            float4 xv = *(const float4*)(x + o);
            Pack4 p4;
            p4.h[0] = __float2bfloat16(xv.x); p4.h[1] = __float2bfloat16(xv.y);
            p4.h[2] = __float2bfloat16(xv.z); p4.h[3] = __float2bfloat16(xv.w);
            *(unsigned long long*)(xb + o) = p4.v;
#pragma unroll
            for (int e = 0; e < NEXP; e++) {
                float4 w4 = *(const float4*)&rw[e * CDIM + c0 + lane * 4];
                acc[e] += xv.x * w4.x + xv.y * w4.y + xv.z * w4.z + xv.w * w4.w;
            }
        }
#pragma unroll
        for (int e = 0; e < NEXP; e++) {
#pragma unroll
            for (int s = 32; s > 0; s >>= 1) acc[e] += __shfl_xor(acc[e], s);
        }
        if (lane == 0) {
            float mx = acc[0];
#pragma unroll
            for (int e = 1; e < NEXP; e++) mx = fmaxf(mx, acc[e]);
            float p[NEXP], se = 0.f;
#pragma unroll
            for (int e = 0; e < NEXP; e++) { p[e] = __expf(acc[e] - mx); se += p[e]; }
            float inv = 1.f / se;
            int i0 = 0;
#pragma unroll
            for (int e = 1; e < NEXP; e++) if (p[e] > p[i0]) i0 = e;
            int i1 = (i0 == 0) ? 1 : 0;
#pragma unroll
            for (int e = 0; e < NEXP; e++) if (e != i0 && p[e] > p[i1]) i1 = e;
            int p0 = atomicAdd(&sh.lcnt[i0], 1);
            sh.lt[i0][p0] = n; sh.lw[i0][p0] = p[i0] * inv;
            int p1 = atomicAdd(&sh.lcnt[i1], 1);
            sh.lt[i1][p1] = n | (1 << 16); sh.lw[i1][p1] = p[i1] * inv;
        }
    }
    __syncthreads();
    if (tid < NEXP) sh.base[tid] = atomicAdd(&cnt[tid * 16], sh.lcnt[tid]);
    __syncthreads();
#pragma unroll
    for (int e = 0; e < NEXP; e++) {
        for (int i = tid; i < sh.lcnt[e]; i += 256) {
            int v = sh.lt[e][i];
            rows[e * NTOK + sh.base[e] + i] = v;
            wts [e * NTOK + sh.base[e] + i] = sh.lw[e][i];
            slotEI[2 * (v & 0xFFFF) + (v >> 16)] = (e << 14) | (sh.base[e] + i);
        }
    }
}

__global__ __launch_bounds__(256) void transpose_conv(
    const float* __restrict__ src, __hip_bfloat16* __restrict__ dst)
{
    __shared__ float t[64][65];
    const int e = blockIdx.z;
    const int r0 = blockIdx.x * 64, c0 = blockIdx.y * 64;
    const int tid = threadIdx.x;
    const int rr = tid >> 4;
    const int cc = (tid & 15) * 4;
#pragma unroll
    for (int j = 0; j < 4; j++) {
        int row = j * 16 + rr;
        float4 v = *(const float4*)(src + ((size_t)e * 1024 + r0 + row) * 1024 + c0 + cc);
        t[row][cc] = v.x; t[row][cc + 1] = v.y; t[row][cc + 2] = v.z; t[row][cc + 3] = v.w;
    }
    __syncthreads();
#pragma unroll
    for (int j = 0; j < 4; j++) {
        int trow = j * 16 + rr;
        Pack4 o;
#pragma unroll
        for (int k = 0; k < 4; k++) o.h[k] = __float2bfloat16(t[cc + k][trow]);
        *(unsigned long long*)(dst + ((size_t)e * 1024 + c0 + trow) * 1024 + r0 + cc) = o.v;
    }
}

// ======== 8-phase 256x256 GEMM core, deep-staged (proven r12/r14 schedule) ========
#define STAGE_A(buf, h, kt) { \
    gload16(asrc[2*(h)]   + (kt)*BK, &smem[buf][0][((2*(h))*512   + wv*64)*8]); \
    gload16(asrc[2*(h)+1] + (kt)*BK, &smem[buf][0][((2*(h)+1)*512 + wv*64)*8]); }
#define STAGE_B(buf, h, kt) { \
    gload16(bsrc[2*(h)]   + (kt)*BK, &smem[buf][1][((2*(h))*512   + wv*64)*8]); \
    gload16(bsrc[2*(h)+1] + (kt)*BK, &smem[buf][1][((2*(h)+1)*512 + wv*64)*8]); }
#define PH_READ_A(buf, mh, ks) { \
    const int cs_ = (((ks)*4 + fq) ^ fx) * 8; \
    _Pragma("unroll") \
    for (int i_ = 0; i_ < 4; i_++) \
        af[i_] = *(const short8*)&smem[buf][0][(wr*128 + (mh)*64 + i_*16 + fr)*64 + cs_]; }
#define PH_READ_B(buf, ks) { \
    const int cs_ = (((ks)*4 + fq) ^ fx) * 8; \
    _Pragma("unroll") \
    for (int n_ = 0; n_ < 4; n_++) \
        bfv[n_] = *(const short8*)&smem[buf][1][(wc*64 + n_*16 + fr)*64 + cs_]; }
#define PH_MFMA(mh) { \
    __builtin_amdgcn_s_setprio(1); \
    _Pragma("unroll") \
    for (int i_ = 0; i_ < 4; i_++) \
        _Pragma("unroll") \
        for (int n_ = 0; n_ < 4; n_++) \
            acc[(mh)*4 + i_][n_] = __builtin_amdgcn_mfma_f32_16x16x32_bf16( \
                af[i_], bfv[n_], acc[(mh)*4 + i_][n_], 0, 0, 0); \
    __builtin_amdgcn_s_setprio(0); }
#define SBAR { \
    __builtin_amdgcn_sched_barrier(0); \
    __builtin_amdgcn_s_barrier(); \
    __builtin_amdgcn_sched_barrier(0); }

#define KLOOP_8PHASE \
    STAGE_A(0, 0, 0); STAGE_A(0, 1, 0); STAGE_B(0, 0, 0); STAGE_B(0, 1, 0); \
    STAGE_B(1, 0, 1); STAGE_B(1, 1, 1); \
    asm volatile("s_waitcnt vmcnt(4)" ::: "memory"); \
    SBAR; \
    _Pragma("unroll 1") \
    for (int j = 0; j < NKT / 2; j++) { \
        const int t2 = 2 * j; \
        const bool full = (j < NKT / 2 - 1); \
        short8 af[4], bfv[4]; \
        /* p1 */ \
        PH_READ_A(0, 0, 0); PH_READ_B(0, 0); \
        STAGE_A(1, 0, t2 + 1); STAGE_A(1, 1, t2 + 1); \
        SBAR; PH_MFMA(0); \
        /* p2 */ \
        PH_READ_A(0, 1, 0); \
        SBAR; PH_MFMA(1); \
        /* p3 */ \
        PH_READ_A(0, 0, 1); PH_READ_B(0, 1); \
        SBAR; PH_MFMA(0); \
        /* p4 */ \
        PH_READ_A(0, 1, 1); \
        if (full) { \
            STAGE_B(0, 0, t2 + 2); STAGE_B(0, 1, t2 + 2); \
            asm volatile("s_waitcnt vmcnt(4)" ::: "memory"); \
        } else { \
            asm volatile("s_waitcnt vmcnt(0)" ::: "memory"); \
        } \
        SBAR; PH_MFMA(1); \
        /* p5 */ \
        PH_READ_A(1, 0, 0); PH_READ_B(1, 0); \
        if (full) { STAGE_A(0, 0, t2 + 2); STAGE_A(0, 1, t2 + 2); } \
        SBAR; PH_MFMA(0); \
        /* p6 */ \
        PH_READ_A(1, 1, 0); \
        SBAR; PH_MFMA(1); \
        /* p7 */ \
        PH_READ_A(1, 0, 1); PH_READ_B(1, 1); \
        SBAR; PH_MFMA(0); \
        /* p8 */ \
        PH_READ_A(1, 1, 1); \
        if (full) { \
            STAGE_B(1, 0, t2 + 3); STAGE_B(1, 1, t2 + 3); \
            asm volatile("s_waitcnt vmcnt(4)" ::: "memory"); \
        } \
        SBAR; PH_MFMA(1); \
    }

// ---------------- GEMM1: hid = relu(Xb[rows] @ w1t^T) ----------------
__global__ __launch_bounds__(512, 1) void moe_gemm1(
    const __hip_bfloat16* __restrict__ xb, const __hip_bfloat16* __restrict__ w1t,
    const int* __restrict__ cnt, const int* __restrict__ rows,
    __hip_bfloat16* __restrict__ hid)
{
    const int bid = blockIdx.x;
    const int tid = threadIdx.x;
    const int lane = tid & 63, wv = tid >> 6;
    const int fr = lane & 15, fq = lane >> 4;
    const int fx = fr & 7;

    __shared__ alignas(16) __hip_bfloat16 smem[2][2][BM * BK];   // 128 KB

    const int swz8 = (((tid & 7) ^ ((tid >> 3) & 7))) * 8;

    if (bid < 256) {
        const int wid = (bid & 7) * 32 + (bid >> 3);
        const int t = wid >> 2;
        int e, m0, off;
        if (!find_full_tile(cnt, t, e, m0, off)) return;
        const int n0 = (wid & 3) * BN;
        const int wr = wv >> 2, wc = wv & 3;

        const __hip_bfloat16* asrc[4];
        const __hip_bfloat16* bsrc[4];
#pragma unroll
        for (int i = 0; i < 4; i++) {
            int row = i * 64 + (tid >> 3);
            int tok = rows[e * NTOK + m0 + row] & 0xFFFF;
            asrc[i] = xb + (size_t)tok * CDIM + swz8;
            bsrc[i] = w1t + ((size_t)e * FDIM + n0 + row) * CDIM + swz8;
        }

        f32x4 acc[8][4] = {};
        KLOOP_8PHASE;
        __syncthreads();

        __hip_bfloat16 (*Cl)[BN] = reinterpret_cast<__hip_bfloat16(*)[BN]>(&smem[0][0][0]);
#pragma unroll
        for (int m = 0; m < 8; m++)
#pragma unroll
            for (int n = 0; n < 4; n++)
#pragma unroll
                for (int r = 0; r < 4; r++) {
                    int il = wr * 128 + m * 16 + fq * 4 + r;
                    float v = acc[m][n][r];
                    Cl[il][wc * 64 + n * 16 + fr] = __float2bfloat16(v > 0.f ? v : 0.f);
                }
        __syncthreads();
#pragma unroll
        for (int i = 0; i < 16; i++) {
            int chunk = i * 512 + tid;
            int row = chunk >> 5, c8 = (chunk & 31) * 8;
            *(short8*)(hid + (size_t)(off + m0 + row) * FDIM + n0 + c8) =
                *(const short8*)&Cl[row][c8];
        }
    } else {
        // ---- 128x128 filler path ----
        const int f = bid - 256;
        const int t = f >> 3;
        int e, m0, off, me;
        if (!find_fill_tile(cnt, t, e, m0, off, me)) return;
        const int n0 = (f & 7) * 128;
        const int wr2 = wv >> 2, wc2 = wv & 3;

        const __hip_bfloat16* asrcF[2];
        const __hip_bfloat16* bsrcF[2];
#pragma unroll
        for (int i = 0; i < 2; i++) {
            int row = i * 64 + (tid >> 3);
            int gi = m0 + row;
            int ri = gi < me ? gi : me - 1;
            int tok = rows[e * NTOK + ri] & 0xFFFF;
            asrcF[i] = xb + (size_t)tok * CDIM + swz8;
            bsrcF[i] = w1t + ((size_t)e * FDIM + n0 + row) * CDIM + swz8;
        }

        f32x4 accF[4][2] = {};

#pragma unroll
        for (int i = 0; i < 2; i++) {
            gload16(asrcF[i], &smem[0][0][(i * 512 + wv * 64) * 8]);
            gload16(bsrcF[i], &smem[0][1][(i * 512 + wv * 64) * 8]);
        }

        int cur = 0;
        for (int kt = 0; kt < NKT; kt++) {
            __builtin_amdgcn_s_barrier();
            if (kt + 1 < NKT) {
                const int k1 = (kt + 1) * BK;
#pragma unroll
                for (int i = 0; i < 2; i++) {
                    gload16(asrcF[i] + k1, &smem[cur ^ 1][0][(i * 512 + wv * 64) * 8]);
                    gload16(bsrcF[i] + k1, &smem[cur ^ 1][1][(i * 512 + wv * 64) * 8]);
                }
                asm volatile("s_waitcnt vmcnt(4)" ::: "memory");
            } else {
                asm volatile("s_waitcnt vmcnt(0)" ::: "memory");
            }
            __builtin_amdgcn_s_barrier();
            __builtin_amdgcn_sched_barrier(0);
#pragma unroll
            for (int ks = 0; ks < 2; ks++) {
                short8 afF[4], bfF[2];
                const int cs = ((ks * 4 + fq) ^ fx) * 8;
#pragma unroll
                for (int m = 0; m < 4; m++)
                    afF[m] = *(const short8*)&smem[cur][0][(wr2 * 64 + m * 16 + fr) * 64 + cs];
#pragma unroll
                for (int n = 0; n < 2; n++)
                    bfF[n] = *(const short8*)&smem[cur][1][(wc2 * 32 + n * 16 + fr) * 64 + cs];
#pragma unroll
                for (int m = 0; m < 4; m++)
#pragma unroll
                    for (int n = 0; n < 2; n++)
                        accF[m][n] = __builtin_amdgcn_mfma_f32_16x16x32_bf16(
                            afF[m], bfF[n], accF[m][n], 0, 0, 0);
            }
            cur ^= 1;
        }
        __syncthreads();

        __hip_bfloat16 (*Cl)[128] = reinterpret_cast<__hip_bfloat16(*)[128]>(&smem[0][0][0]);
#pragma unroll
        for (int m = 0; m < 4; m++)
#pragma unroll
            for (int n = 0; n < 2; n++)
#pragma unroll
                for (int r = 0; r < 4; r++) {
                    int il = wr2 * 64 + m * 16 + fq * 4 + r;
                    float v = accF[m][n][r];
                    Cl[il][wc2 * 32 + n * 16 + fr] = __float2bfloat16(v > 0.f ? v : 0.f);
                }
        __syncthreads();
#pragma unroll
        for (int i = 0; i < 4; i++) {
            int chunk = i * 512 + tid;
            int row = chunk >> 4, c8 = (chunk & 15) * 8;
            int gi = m0 + row;
            if (gi < me)
                *(short8*)(hid + (size_t)(off + gi) * FDIM + n0 + c8) =
                    *(const short8*)&Cl[row][c8];
        }
    }
}

// ------- GEMM2: ybuf[slot] = wt * (hid @ w2t^T) (or atomic fallback) -------
__global__ __launch_bounds__(512, 1) void moe_gemm2(
    const __hip_bfloat16* __restrict__ hid, const __hip_bfloat16* __restrict__ w2t,
    const int* __restrict__ cnt, const int* __restrict__ rows,
    const float* __restrict__ wts, __hip_bfloat16* __restrict__ ybuf,
    float* __restrict__ out)
{
    const int bid = blockIdx.x;
    const int tid = threadIdx.x;
    const int lane = tid & 63, wv = tid >> 6;
    const int fr = lane & 15, fq = lane >> 4;
    const int fx = fr & 7;

    __shared__ alignas(16) __hip_bfloat16 smem[2][2][BM * BK];
    __shared__ int rtok[BM];
    __shared__ float rwt[BM];

    const int swz8 = (((tid & 7) ^ ((tid >> 3) & 7))) * 8;

    if (bid < 256) {
        const int wid = (bid & 7) * 32 + (bid >> 3);
        const int t = wid >> 2;
        int e, m0, off;
        if (!find_full_tile(cnt, t, e, m0, off)) return;
        const int n0 = (wid & 3) * BN;
        const int wr = wv >> 2, wc = wv & 3;

        if (tid < BM) {
            rtok[tid] = rows[e * NTOK + m0 + tid] & 0xFFFF;
            rwt[tid] = wts[e * NTOK + m0 + tid];
        }
        __syncthreads();

        const __hip_bfloat16* asrc[4];
        const __hip_bfloat16* bsrc[4];
#pragma unroll
        for (int i = 0; i < 4; i++) {
            int row = i * 64 + (tid >> 3);
            asrc[i] = hid + (size_t)(off + m0 + row) * FDIM + swz8;
            bsrc[i] = w2t + ((size_t)e * CDIM + n0 + row) * FDIM + swz8;
        }

        f32x4 acc[8][4] = {};
        KLOOP_8PHASE;
        __syncthreads();

        if (ybuf) {
            __hip_bfloat16 (*Cl)[BN] = reinterpret_cast<__hip_bfloat16(*)[BN]>(&smem[0][0][0]);
#pragma unroll
            for (int m = 0; m < 8; m++)
#pragma unroll
                for (int n = 0; n < 4; n++)
#pragma unroll
                    for (int r = 0; r < 4; r++) {
                        int il = wr * 128 + m * 16 + fq * 4 + r;
                        Cl[il][wc * 64 + n * 16 + fr] =
                            __float2bfloat16(rwt[il] * acc[m][n][r]);
                    }
            __syncthreads();
#pragma unroll
            for (int i = 0; i < 16; i++) {
                int chunk = i * 512 + tid;
                int row = chunk >> 5, c8 = (chunk & 31) * 8;
                *(short8*)(ybuf + (size_t)(off + m0 + row) * CDIM + n0 + c8) =
                    *(const short8*)&Cl[row][c8];
            }
        } else {
#pragma unroll
            for (int m = 0; m < 8; m++)
#pragma unroll
                for (int n = 0; n < 4; n++)
#pragma unroll
                    for (int r = 0; r < 4; r++) {
                        int il = wr * 128 + m * 16 + fq * 4 + r;
                        atomicAdd(&out[(size_t)rtok[il] * CDIM + n0 + wc * 64 + n * 16 + fr],
                                  rwt[il] * acc[m][n][r]);
                    }
        }
    } else {
        // ---- 128x128 filler path ----
        const int f = bid - 256;
        const int t = f >> 3;
        int e, m0, off, me;
        if (!find_fill_tile(cnt, t, e, m0, off, me)) return;
        const int n0 = (f & 7) * 128;
        const int wr2 = wv >> 2, wc2 = wv & 3;

        if (tid < 128) {
            int gi = m0 + tid;
            int ri = gi < me ? gi : me - 1;
            rtok[tid] = rows[e * NTOK + ri] & 0xFFFF;
            rwt[tid] = gi < me ? wts[e * NTOK + ri] : 0.f;
        }
        __syncthreads();

        const __hip_bfloat16* asrcF[2];
        const __hip_bfloat16* bsrcF[2];
#pragma unroll
        for (int i = 0; i < 2; i++) {
            int row = i * 64 + (tid >> 3);
            int gi = m0 + row;
            int ri = gi < me ? gi : me - 1;
            asrcF[i] = hid + (size_t)(off + ri) * FDIM + swz8;
            bsrcF[i] = w2t + ((size_t)e * CDIM + n0 + row) * FDIM + swz8;
        }

        f32x4 accF[4][2] = {};

#pragma unroll
        for (int i = 0; i < 2; i++) {
            gload16(asrcF[i], &smem[0][0][(i * 512 + wv * 64) * 8]);
            gload16(bsrcF[i], &smem[0][1][(i * 512 + wv * 64) * 8]);
        }

        int cur = 0;
        for (int kt = 0; kt < NKT; kt++) {
            __builtin_amdgcn_s_barrier();
            if (kt + 1 < NKT) {
                const int k1 = (kt + 1) * BK;
#pragma unroll
                for (int i = 0; i < 2; i++) {
                    gload16(asrcF[i] + k1, &smem[cur ^ 1][0][(i * 512 + wv * 64) * 8]);
                    gload16(bsrcF[i] + k1, &smem[cur ^ 1][1][(i * 512 + wv * 64) * 8]);
                }
                asm volatile("s_waitcnt vmcnt(4)" ::: "memory");
            } else {
                asm volatile("s_waitcnt vmcnt(0)" ::: "memory");
            }
            __builtin_amdgcn_s_barrier();
            __builtin_amdgcn_sched_barrier(0);
#pragma unroll
            for (int ks = 0; ks < 2; ks++) {
                short8 afF[4], bfF[2];
                const int cs = ((ks * 4 + fq) ^ fx) * 8;
#pragma unroll
                for (int m = 0; m < 4; m++)
                    afF[m] = *(const short8*)&smem[cur][0][(wr2 * 64 + m * 16 + fr) * 64 + cs];
#pragma unroll
                for (int n = 0; n < 2; n++)
                    bfF[n] = *(const short8*)&smem[cur][1][(wc2 * 32 + n * 16 + fr) * 64 + cs];
#pragma unroll
                for (int m = 0; m < 4; m++)
#pragma unroll
                    for (int n = 0; n < 2; n++)
                        accF[m][n] = __builtin_amdgcn_mfma_f32_16x16x32_bf16(
                            afF[m], bfF[n], accF[m][n], 0, 0, 0);
            }
            cur ^= 1;
        }
        __syncthreads();

        if (ybuf) {
            __hip_bfloat16 (*Cl)[128] = reinterpret_cast<__hip_bfloat16(*)[128]>(&smem[0][0][0]);
#pragma unroll
            for (int m = 0; m < 4; m++)
#pragma unroll
                for (int n = 0; n < 2; n++)
#pragma unroll
                    for (int r = 0; r < 4; r++) {
                        int il = wr2 * 64 + m * 16 + fq * 4 + r;
                        Cl[il][wc2 * 32 + n * 16 + fr] =
                            __float2bfloat16(rwt[il] * accF[m][n][r]);
                    }
            __syncthreads();
#pragma unroll
            for (int i = 0; i < 4; i++) {
                int chunk = i * 512 + tid;
                int row = chunk >> 4, c8 = (chunk & 15) * 8;
                int gi = m0 + row;
                if (gi < me)
                    *(short8*)(ybuf + (size_t)(off + gi) * CDIM + n0 + c8) =
                        *(const short8*)&Cl[row][c8];
            }
        } else {
#pragma unroll
            for (int m = 0; m < 4; m++)
#pragma unroll
                for (int n = 0; n < 2; n++)
#pragma unroll
                    for (int r = 0; r < 4; r++) {
                        int il = wr2 * 64 + m * 16 + fq * 4 + r;
                        int gi = m0 + il;
                        if (gi < me)
                            atomicAdd(&out[(size_t)rtok[il] * CDIM + n0 + wc2 * 32 + n * 16 + fr],
                                      rwt[il] * accF[m][n][r]);
                    }
        }
    }
}

// ---------------- gather: out[n] = y[slot0] + y[slot1] ----------------
__global__ __launch_bounds__(256) void gather_out(
    const __hip_bfloat16* __restrict__ yb, const int* __restrict__ slotEI,
    const int* __restrict__ cnt, float* __restrict__ out)
{
    for (int n = blockIdx.x; n < NTOK; n += gridDim.x) {
        const int v0 = slotEI[2 * n], v1 = slotEI[2 * n + 1];
        int e0 = v0 >> 14, e1 = v1 >> 14;
        int s0 = v0 & 0x3FFF, s1 = v1 & 0x3FFF;
        for (int ee = 0; ee < NEXP; ee++) {
            int me = cnt[ee * 16];
            if (ee < e0) s0 += me;
            if (ee < e1) s1 += me;
        }
        const int c = threadIdx.x * 4;
        U4 a, b;
        a.u = *(const unsigned long long*)(yb + (size_t)s0 * CDIM + c);
        b.u = *(const unsigned long long*)(yb + (size_t)s1 * CDIM + c);
        float4 o;
        o.x = bf2f(a.s[0]) + bf2f(b.s[0]);
        o.y = bf2f(a.s[1]) + bf2f(b.s[1]);
        o.z = bf2f(a.s[2]) + bf2f(b.s[2]);
        o.w = bf2f(a.s[3]) + bf2f(b.s[3]);
        *(float4*)(out + (size_t)n * CDIM + c) = o;
    }
}

// ---------------- launch ----------------
extern "C" void kernel_launch(void* const* d_in, const int* in_sizes, int n_in,
                              void* d_out, int out_size, void* d_ws, size_t ws_size,
                              hipStream_t stream)
{
    const float* x  = (const float*)d_in[0];
    const float* rw = (const float*)d_in[1];
    const float* w1 = (const float*)d_in[2];
    const float* w2 = (const float*)d_in[3];
    float* out = (float*)d_out;
    char* ws = (char*)d_ws;

    int* cnt  = (int*)ws;                                  // 8 counters, 64B stride
    int* rows = (int*)(ws + 4096);                         // [E][NTOK]
    float* wts = (float*)(ws + 4096 + NEXP * NTOK * 4);
    int* slotEI = (int*)(ws + 4096 + 2 * NEXP * NTOK * 4); // [NTOK][2]

    hipMemsetAsync(cnt, 0, 1024, stream);

    const bool big = ws_size >= ((size_t)81 << 20);
    if (big) {
        // layout: xb 1-17, w1t 17-33, w2t 33-49, hid 49-81, ybuf overlays 1-33
        __hip_bfloat16* xb  = (__hip_bfloat16*)(ws + (1u << 20));
        __hip_bfloat16* w1t = (__hip_bfloat16*)(ws + (17u << 20));
        __hip_bfloat16* w2t = (__hip_bfloat16*)(ws + (33u << 20));
        __hip_bfloat16* hid = (__hip_bfloat16*)(ws + (49u << 20));
        __hip_bfloat16* ybuf = (__hip_bfloat16*)(ws + (1u << 20));  // xb+w1t dead after gemm1

        router_transpose<<<512 + 4096, 256, 0, stream>>>(
            x, rw, xb, cnt, rows, wts, slotEI, w1, w2, w1t, w2t);
        moe_gemm1<<<NWG, 512, 0, stream>>>(xb, w1t, cnt, rows, hid);
        moe_gemm2<<<NWG, 512, 0, stream>>>(hid, w2t, cnt, rows, wts, ybuf, out);
        gather_out<<<2048, 256, 0, stream>>>(ybuf, slotEI, cnt, out);
    } else {
        // compact fallback: w2t aliases w1t (transposed after gemm1), atomic epilogue
        __hip_bfloat16* xb  = (__hip_bfloat16*)(ws + (1u << 20));
        __hip_bfloat16* w1t = (__hip_bfloat16*)(ws + (17u << 20));
        __hip_bfloat16* hid = (__hip_bfloat16*)(ws + (33u << 20));
        __hip_bfloat16* w2t = w1t;

        hipMemsetAsync(d_out, 0, (size_t)out_size * sizeof(float), stream);
        router_kernel<<<NTOK / 16, 256, 0, stream>>>(x, rw, xb, cnt, rows, wts, slotEI);
        transpose_conv<<<dim3(16, 16, NEXP), 256, 0, stream>>>(w1, w1t);
        moe_gemm1<<<NWG, 512, 0, stream>>>(xb, w1t, cnt, rows, hid);
        transpose_conv<<<dim3(16, 16, NEXP), 256, 0, stream>>>(w2, w2t);
        moe_gemm2<<<NWG, 512, 0, stream>>>(hid, w2t, cnt, rows, wts, nullptr, out);
    }
}